// Round 12
// baseline (1518.032 us; speedup 1.0000x reference)
//
#include <hip/hip_runtime.h>
#include <hip/hip_bf16.h>
#include <hip/hip_cooperative_groups.h>

namespace cg = cooperative_groups;

typedef unsigned int u32;
typedef unsigned short u16;

#define DEVINL __device__ __forceinline__

constexpr int Nn  = 25000;
constexpr int Ee  = 100000;
constexpr int NCc = 8000;
constexpr int Aa  = 50000;
constexpr int ECc = 24000;
constexpr int TCOLS = 1088;
constexpr int WPSZ  = TCOLS*32;
constexpr int NSTR  = 580;      // LDS T node stride in u32
constexpr int NBN5 = (Nn + 511)/512;    // 49 scan chunks (node-sized segs)
constexpr int NBC5 = (NCc + 511)/512;   // 16 scan chunks (clique-sized segs)
constexpr int NCHUNK = 3*(NBN5 + NBC5); // 195

typedef float f32x4 __attribute__((ext_vector_type(4)));
typedef short s16x8 __attribute__((ext_vector_type(8)));

DEVINL float b2f(u16 u){ union{u32 i;float f;}v; v.i = ((u32)u)<<16; return v.f; }
DEVINL float bfl(u32 u){ union{u32 i;float f;}v; v.i = u<<16; return v.f; }
DEVINL float bfh(u32 u){ union{u32 i;float f;}v; v.i = u & 0xffff0000u; return v.f; }
DEVINL u16 f2b(float f){ union{float f;u32 i;}v; v.f=f; u32 i=v.i;
  return (u16)((i + 0x7fffu + ((i>>16)&1u)) >> 16); }
DEVINL u32 pk2(float a, float b){ return (u32)f2b(a) | ((u32)f2b(b) << 16); }
DEVINL float ldw(const void* p, long i, int f){
  return f ? ((const float*)p)[i] : b2f(((const u16*)p)[i]);
}

struct P {
  const void *xin, *cin, *ef, *cef;
  const int *ei, *cei, *n2c;
  const void *nn1w,*nn1b,*nn2w,*nn2b,*rootw,*rootb,*n2cw,*n2cb;
  const void *cnn1w,*cnn1b,*cnn2w,*cnn2b,*crootw,*crootb,*c2nw,*c2nb;
  int *zbase; int znum;
  int *deg_nd,*deg_ce,*deg_n2c,*deg_c2n,*cnt_sn,*cnt_sc;
  int *cur_n,*cur_c,*cur_an,*cur_ac,*curd_n,*curd_c;
  u32* maxbits; int* zcnt;
  float *xA,*xB,*xC,*cA,*cC0,*m_n,*m_c,*frn,*frc;
  int *offs_n,*offs_c,*offs_an,*offs_ac,*doffs_n,*doffs_c;
  int *bs0,*bs1,*bs2,*bs3,*bs4,*bs5;
  int *perm_n,*perm_c,*dq_n,*dq_c,*an2c,*ac2n;
  int2 *sdp_n,*sdp_c; float *efp_n,*efp_c;
  u32 *msg_n,*msg_c;
  u16* Wp4;
  void* out;
};

// ---------- conv stage (persistent windows): MFMA T in LDS + streaming edges ----------
DEVINL void dev_conv(u32* SM, const P& p, int f,
                     const float* base, const float* mprev, const int* aidx,
                     const int* aoffs, const int* adeg, int M,
                     const int2* sdp, const float* efp, const int* offs, int E_,
                     const void* w1, long w1off, const void* b1, long b1off,
                     const u16* Wp, const void* rb, long rboff,
                     float* feat_root, u32* msg){
  u32* Ts = SM;
  float* w1s = (float*)(SM + 9280);
  u32* hwb = SM + 9536;
  int tid = threadIdx.x;
  int w = tid >> 6, lane = tid & 63;
  int quad = lane >> 4, lm = lane & 15;
  if (tid < 256) w1s[tid] = ldw(w1, w1off + tid, f);
  float bb0 = ldw(b1, b1off + 2*lm, f);
  float bb1 = ldw(b1, b1off + 2*lm + 1, f);
  u32* hw = hwb + w*64;
  int G = (M + 15)/16;
  for (int win = blockIdx.x; win < G; win += gridDim.x){
    __syncthreads();   // protect Ts reuse + w1s visibility
    int n0 = win * 16;
    int n = n0 + lm;
    int nc = n < M ? n : M-1;
    const float* bp = base + (size_t)nc*32 + quad*8;
    float fv[8];
    #pragma unroll
    for (int j = 0; j < 8; j++) fv[j] = bp[j];
    if (aidx){
      int lo = aoffs[nc], cnt = adeg[nc];
      float sacc[8] = {0,0,0,0,0,0,0,0};
      for (int a = lo; a < lo + cnt; a++){
        const float* mp = mprev + (size_t)aidx[a]*32 + quad*8;
        #pragma unroll
        for (int j = 0; j < 8; j++) sacc[j] += mp[j];
      }
      float inv = 1.f/(float)(cnt > 1 ? cnt : 1);
      #pragma unroll
      for (int j = 0; j < 8; j++) fv[j] += sacc[j]*inv;
    }
    s16x8 bfrag;
    #pragma unroll
    for (int j = 0; j < 8; j++) bfrag[j] = (short)f2b(fv[j]);
    #pragma unroll 1
    for (int ti = 0; ti < 9; ti++){
      int ct = w*9 + ti;
      if (ct >= 68) break;
      int colbase = ct*16;
      s16x8 afrag = *(const s16x8*)(Wp + (size_t)(colbase + lm)*32 + quad*8);
      f32x4 acc = {0.f, 0.f, 0.f, 0.f};
      acc = __builtin_amdgcn_mfma_f32_16x16x32_bf16(afrag, bfrag, acc, 0, 0, 0);
      if (ct < 66){
        int k = ct >> 1;
        int p0 = (ct & 1)*8 + quad*2;
        int idx = lm*NSTR + p0*36 + k;
        Ts[idx]      = pk2(acc[0], acc[1]);
        Ts[idx + 36] = pk2(acc[2], acc[3]);
      } else if (n < M){
        int o = (colbase + quad*4) - 1056;
        float4 v = make_float4(acc[0] + ldw(rb, rboff+o,   f),
                               acc[1] + ldw(rb, rboff+o+1, f),
                               acc[2] + ldw(rb, rboff+o+2, f),
                               acc[3] + ldw(rb, rboff+o+3, f));
        *(float4*)&feat_root[(size_t)n*32 + o] = v;
      }
    }
    __syncthreads();
    int lo = offs[n0];
    int hi = (n0 + 16 < M) ? offs[n0 + 16] : E_;
    int eg = quad, kk = lm;
    int pos = lo + w*4;
    float ef0 = 0.f, ef1 = 0.f; int sd0 = 0, sd1 = 0;
    if (lane < 32){
      int idx = pos*8 + lane;        if (idx < hi*8) ef0 = efp[idx];
      idx = (pos+32)*8 + lane;       if (idx < hi*8) ef1 = efp[idx];
    } else if (lane < 40){
      int idx = pos*2 + (lane-32);   if (idx < hi*2) sd0 = ((const int*)sdp)[idx];
      idx = (pos+32)*2 + (lane-32);  if (idx < hi*2) sd1 = ((const int*)sdp)[idx];
    }
    for (; pos < hi; pos += 32){
      int np = pos + 64;
      float ef2 = 0.f; int sd2 = 0;
      if (lane < 32){ int idx = np*8 + lane; if (idx < hi*8) ef2 = efp[idx]; }
      else if (lane < 40){ int idx = np*2 + (lane-32); if (idx < hi*2) sd2 = ((const int*)sdp)[idx]; }
      int sn = __shfl(sd0, 32 + 2*eg);
      int dq = __shfl(sd0, 33 + 2*eg);
      bool valid = (pos + eg < hi);
      int sr = sn - n0; sr = sr < 0 ? 0 : (sr > 15 ? 15 : sr);
      float a0 = bb0, a1 = bb1;
      #pragma unroll
      for (int j = 0; j < 8; j++){
        float ev = __shfl(ef0, eg*8 + j);
        a0 += ev * w1s[j*32 + 2*kk];
        a1 += ev * w1s[j*32 + 2*kk+1];
      }
      hw[eg*16 + kk] = pk2(fmaxf(a0, 0.f), fmaxf(a1, 0.f));
      if (valid){
        const u32* Tr = &Ts[sr*NSTR + kk*36];
        u32 vb = Tr[32];
        float m0 = bfl(vb), m1 = bfh(vb);
        #pragma unroll
        for (int g = 0; g < 8; g++){
          uint4 tv = *(const uint4*)&Tr[g*4];
          uint2 hp = *(const uint2*)&hw[eg*16 + g*2];
          float h0 = bfl(hp.x), h1 = bfh(hp.x), h2 = bfl(hp.y), h3 = bfh(hp.y);
          m0 += h0*bfl(tv.x) + h1*bfl(tv.y) + h2*bfl(tv.z) + h3*bfl(tv.w);
          m1 += h0*bfh(tv.x) + h1*bfh(tv.y) + h2*bfh(tv.z) + h3*bfh(tv.w);
        }
        msg[(size_t)dq*16 + kk] = pk2(m0, m1);
      }
      ef0 = ef1; sd0 = sd1; ef1 = ef2; sd1 = sd2;
    }
  }
}

// ---------- update stage: feat = relu(segsum(msg)/deg + froot); m = feat@w+b ----------
DEVINL void dev_update(u32* SM, int f, const u32* msg,
                       const int* doffs, const int* ddeg, const float* froot, int M,
                       const void* w, long woff, const void* b, long boff,
                       float* feat, void* dt_out, long dt_off, float* m_out){
  float* wsm = (float*)SM;
  float* bs = (float*)(SM + 1024);
  float (*rows)[33] = (float(*)[33])(SM + 1056);
  int tid = threadIdx.x;
  for (int idx = tid; idx < 1024; idx += 512) wsm[idx] = ldw(w, woff + idx, f);
  if (tid < 32) bs[tid] = ldw(b, boff + tid, f);
  __syncthreads();
  int nl = tid >> 5, o = tid & 31;
  int G = (M + 15)/16;
  for (int grp = blockIdx.x; grp < G; grp += gridDim.x){
    int n = grp*16 + nl;
    if (n < M){
      long i = (long)n*32 + o;
      int lo = doffs[n], cnt = ddeg[n];
      const u16* mp = (const u16*)msg;
      float s = 0.f;
      for (int a = 0; a < cnt; a++) s += b2f(mp[(size_t)(lo+a)*32 + o]);
      float v = fmaxf(s/(float)(cnt > 1 ? cnt : 1) + froot[i], 0.f);
      rows[nl][o] = v;   // wave-local RAW only
      if (feat) feat[i] = v;
      if (dt_out){
        if (f) ((float*)dt_out)[dt_off + i] = v;
        else   ((u16*)dt_out)[dt_off + i]   = f2b(v);
      }
      float acc = bs[o];
      #pragma unroll
      for (int j = 0; j < 32; j++) acc += rows[nl][j]*wsm[j*32+o];
      m_out[i] = acc;
    }
  }
}

__global__ __launch_bounds__(512) void k_mega(P p){
  cg::grid_group grid = cg::this_grid();
  __shared__ __align__(16) u32 SM[10368];
  int tid = threadIdx.x;
  int bid = blockIdx.x;
  int gstride = gridDim.x * 512;
  #define GSTRIDE(i, N) for (int i = bid*512 + tid; i < (N); i += gstride)
  #define GSYNC() do { __threadfence(); grid.sync(); } while(0)

  // ---- S0: zero counters ----
  GSTRIDE(i, p.znum) p.zbase[i] = 0;
  GSYNC();

  // ---- S1: dtype detect ----
  {
    const u16* xp = (const u16*)p.xin;
    float lm = 0.f; int lz = 0;
    GSTRIDE(i, Nn*32){
      u16 v = xp[i];
      if (v == 0) lz++;
      lm = fmaxf(lm, fabsf(b2f(v)));
    }
    #pragma unroll
    for (int off = 32; off; off >>= 1){
      lm = fmaxf(lm, __shfl_down(lm, off));
      lz += __shfl_down(lz, off);
    }
    if ((tid & 63) == 0){
      atomicMax(p.maxbits, __float_as_uint(lm));
      atomicAdd(p.zcnt, lz);
    }
  }
  GSYNC();
  const int f = (__uint_as_float(*p.maxbits) > 1e6f || *p.zcnt > (Nn*32)/4) ? 1 : 0;

  // ---- S2: feature convert + weight pack + histograms ----
  GSTRIDE(i, Nn*32) p.xA[i] = ldw(p.xin, i, f);
  GSTRIDE(i, NCc*32) p.cA[i] = ldw(p.cin, i, f);
  GSTRIDE(i, 4*WPSZ){
    int set = i / WPSZ, j = i - set*WPSZ;
    int l = set >> 1, isC = set & 1;
    const void* W2 = isC ? p.cnn2w : p.nn2w;
    const void* B2 = isC ? p.cnn2b : p.nn2b;
    const void* RW = isC ? p.crootw : p.rootw;
    int col = j >> 5, ii = j & 31;
    float v;
    if (col < 1024)      v = ldw(W2, (long)l*32768 + ((col>>5)<<10) + (ii<<5) + (col&31), f);
    else if (col < 1056) v = ldw(B2, (long)l*1024 + (ii<<5) + (col-1024), f);
    else                 v = ldw(RW, (long)l*1024 + (ii<<5) + (col-1056), f);
    p.Wp4[i] = f2b(v);
  }
  GSTRIDE(i0, 2*Ee + 2*ECc + 2*Aa){
    int i = i0;
    if (i < Ee)                 atomicAdd(&p.deg_nd[p.ei[Ee + i]], 1);
    else if ((i -= Ee) < ECc)   atomicAdd(&p.deg_ce[p.cei[ECc + i]], 1);
    else if ((i -= ECc) < Aa)   atomicAdd(&p.deg_n2c[p.n2c[Aa + i]], 1);
    else if ((i -= Aa) < Aa)    atomicAdd(&p.deg_c2n[p.n2c[i]], 1);
    else if ((i -= Aa) < Ee)    atomicAdd(&p.cnt_sn[p.ei[i]], 1);
    else if ((i -= Ee) < ECc)   atomicAdd(&p.cnt_sc[p.cei[i]], 1);
  }
  GSYNC();

  // ---- S3: per-chunk scan (6 segments, 512-wide chunks) ----
  {
    int* s = (int*)SM;
    for (int c = bid; c < NCHUNK; c += gridDim.x){
      __syncthreads();
      int cc = c, seg = 0;
      for (;;){
        int nb = (seg & 1) ? NBC5 : NBN5;
        if (cc < nb) break;
        cc -= nb; seg++;
      }
      const int* cnt = seg==0?p.cnt_sn : seg==1?p.cnt_sc : seg==2?p.deg_c2n :
                       seg==3?p.deg_n2c : seg==4?p.deg_nd : p.deg_ce;
      int* offs = seg==0?p.offs_n : seg==1?p.offs_c : seg==2?p.offs_an :
                  seg==3?p.offs_ac : seg==4?p.doffs_n : p.doffs_c;
      int* bs   = seg==0?p.bs0 : seg==1?p.bs1 : seg==2?p.bs2 :
                  seg==3?p.bs3 : seg==4?p.bs4 : p.bs5;
      int M = (seg & 1) ? NCc : Nn;
      int i = cc*512 + tid;
      int v = (i < M) ? cnt[i] : 0;
      s[tid] = v; __syncthreads();
      for (int d = 1; d < 512; d <<= 1){
        int t = (tid >= d) ? s[tid-d] : 0;
        __syncthreads();
        s[tid] += t;
        __syncthreads();
      }
      if (i < M) offs[i] = s[tid] - v;
      if (tid == 511) bs[cc] = s[511];
    }
  }
  GSYNC();

  // ---- S4: spine (block 0, waves 0..5) ----
  if (bid == 0){
    int wv = tid >> 6, lane = tid & 63;
    if (wv < 6){
      int NB = (wv & 1) ? NBC5 : NBN5;
      int* bp = wv==0?p.bs0 : wv==1?p.bs1 : wv==2?p.bs2 : wv==3?p.bs3 : wv==4?p.bs4 : p.bs5;
      int v0 = (lane < NB) ? bp[lane] : 0;
      int x = v0;
      #pragma unroll
      for (int d = 1; d < 64; d <<= 1){ int t = __shfl_up(x, d); if (lane >= d) x += t; }
      if (lane < NB) bp[lane] = x - v0;
    }
  }
  GSYNC();

  // ---- S5: scan fix ----
  GSTRIDE(i0, 3*(Nn+NCc)){
    int i = i0;
    if (i < Nn) p.offs_n[i] += p.bs0[i >> 9];
    else if ((i -= Nn) < NCc) p.offs_c[i] += p.bs1[i >> 9];
    else if ((i -= NCc) < Nn) p.offs_an[i] += p.bs2[i >> 9];
    else if ((i -= Nn) < NCc) p.offs_ac[i] += p.bs3[i >> 9];
    else if ((i -= NCc) < Nn) p.doffs_n[i] += p.bs4[i >> 9];
    else if ((i -= Nn) < NCc) p.doffs_c[i] += p.bs5[i >> 9];
  }
  GSYNC();

  // ---- S6: place ----
  GSTRIDE(i0, Ee + ECc + 2*Aa){
    int i = i0;
    if (i < Ee){
      int s = p.ei[i], d = p.ei[Ee + i];
      int pp = p.offs_n[s] + atomicAdd(&p.cur_n[s], 1);
      int q = p.doffs_n[d] + atomicAdd(&p.curd_n[d], 1);
      p.perm_n[pp] = i; p.dq_n[pp] = q;
    } else if ((i -= Ee) < ECc){
      int s = p.cei[i], d = p.cei[ECc + i];
      int pp = p.offs_c[s] + atomicAdd(&p.cur_c[s], 1);
      int q = p.doffs_c[d] + atomicAdd(&p.curd_c[d], 1);
      p.perm_c[pp] = i; p.dq_c[pp] = q;
    } else if ((i -= ECc) < Aa){
      int c = p.n2c[Aa + i];
      p.an2c[p.offs_ac[c] + atomicAdd(&p.cur_ac[c], 1)] = p.n2c[i];
    } else if ((i -= Aa) < Aa){
      int nd = p.n2c[i];
      p.ac2n[p.offs_an[nd] + atomicAdd(&p.cur_an[nd], 1)] = p.n2c[Aa + i];
    }
  }
  GSYNC();

  // ---- S7: gather edge payloads ----
  GSTRIDE(i0, 8*(Ee + ECc)){
    int i = i0;
    if (i < Ee*8){
      int pp = i >> 3, j = i & 7;
      int e = p.perm_n[pp];
      p.efp_n[i] = ldw(p.ef, (long)e*8 + j, f);
      if (j == 0) p.sdp_n[pp] = make_int2(p.ei[e], p.dq_n[pp]);
    } else if ((i -= Ee*8) < ECc*8){
      int pp = i >> 3, j = i & 7;
      int e = p.perm_c[pp];
      p.efp_c[i] = ldw(p.cef, (long)e*8 + j, f);
      if (j == 0) p.sdp_c[pp] = make_int2(p.cei[e], p.dq_c[pp]);
    }
  }
  GSYNC();

  // ---- layer 0 ----
  dev_conv(SM, p, f, p.xA, nullptr, nullptr, nullptr, nullptr, Nn,
           p.sdp_n, p.efp_n, p.offs_n, Ee, p.nn1w, 0, p.nn1b, 0,
           p.Wp4 + 0*WPSZ, p.rootb, 0, p.frn, p.msg_n);
  GSYNC();
  dev_update(SM, f, p.msg_n, p.doffs_n, p.deg_nd, p.frn, Nn,
             p.n2cw, 0, p.n2cb, 0, p.xB, nullptr, 0, p.m_n);
  GSYNC();
  dev_conv(SM, p, f, p.cA, p.m_n, p.an2c, p.offs_ac, p.deg_n2c, NCc,
           p.sdp_c, p.efp_c, p.offs_c, ECc, p.cnn1w, 0, p.cnn1b, 0,
           p.Wp4 + 1*WPSZ, p.crootb, 0, p.frc, p.msg_c);
  GSYNC();
  dev_update(SM, f, p.msg_c, p.doffs_c, p.deg_ce, p.frc, NCc,
             p.c2nw, 0, p.c2nb, 0, p.cC0, nullptr, 0, p.m_c);
  GSYNC();
  // ---- layer 1 ----
  dev_conv(SM, p, f, p.xB, p.m_c, p.ac2n, p.offs_an, p.deg_c2n, Nn,
           p.sdp_n, p.efp_n, p.offs_n, Ee, p.nn1w, 256, p.nn1b, 32,
           p.Wp4 + 2*WPSZ, p.rootb, 32, p.frn, p.msg_n);
  GSYNC();
  dev_update(SM, f, p.msg_n, p.doffs_n, p.deg_nd, p.frn, Nn,
             p.n2cw, 1024, p.n2cb, 32, p.xC, nullptr, 0, p.m_n);
  GSYNC();
  dev_conv(SM, p, f, p.cC0, p.m_n, p.an2c, p.offs_ac, p.deg_n2c, NCc,
           p.sdp_c, p.efp_c, p.offs_c, ECc, p.cnn1w, 256, p.cnn1b, 32,
           p.Wp4 + 3*WPSZ, p.crootb, 32, p.frc, p.msg_c);
  GSYNC();
  dev_update(SM, f, p.msg_c, p.doffs_c, p.deg_ce, p.frc, NCc,
             p.c2nw, 1024, p.c2nb, 32, nullptr, p.out, (long)Nn*32, p.m_c);
  GSYNC();
  // ---- final x output ----
  GSTRIDE(i, Nn*32){
    int c = i >> 5, o = i & 31;
    int lo = p.offs_an[c], cnt = p.deg_c2n[c];
    float s = 0.f;
    for (int a = lo; a < lo + cnt; a++) s += p.m_c[(size_t)p.ac2n[a]*32 + o];
    float v = p.xC[i] + s/(float)(cnt > 1 ? cnt : 1);
    if (f) ((float*)p.out)[i] = v;
    else   ((u16*)p.out)[i]   = f2b(v);
  }
  #undef GSTRIDE
  #undef GSYNC
}

extern "C" void kernel_launch(void* const* d_in, const int* in_sizes, int n_in,
                              void* d_out, int out_size, void* d_ws, size_t ws_size,
                              hipStream_t stream){
  P p;
  p.xin = d_in[0]; p.ei = (const int*)d_in[1]; p.ef = d_in[2]; p.cin = d_in[3];
  p.n2c = (const int*)d_in[4]; p.cei = (const int*)d_in[5]; p.cef = d_in[6];
  p.nn1w = d_in[7]; p.nn1b = d_in[8]; p.nn2w = d_in[9]; p.nn2b = d_in[10];
  p.rootw = d_in[11]; p.rootb = d_in[12]; p.n2cw = d_in[13]; p.n2cb = d_in[14];
  p.cnn1w = d_in[15]; p.cnn1b = d_in[16]; p.cnn2w = d_in[17]; p.cnn2b = d_in[18];
  p.crootw = d_in[19]; p.crootb = d_in[20]; p.c2nw = d_in[21]; p.c2nb = d_in[22];
  p.out = d_out;

  char* ws = (char*)d_ws;
  size_t off = 0;
  auto alloc = [&](size_t bytes){ void* q = ws + off; off += (bytes + 255) & ~(size_t)255; return q; };

  // zeroed region
  size_t zstart = off;
  p.deg_nd  = (int*)alloc((size_t)Nn*4);
  p.deg_ce  = (int*)alloc((size_t)NCc*4);
  p.deg_n2c = (int*)alloc((size_t)NCc*4);
  p.deg_c2n = (int*)alloc((size_t)Nn*4);
  p.cnt_sn  = (int*)alloc((size_t)Nn*4);
  p.cnt_sc  = (int*)alloc((size_t)NCc*4);
  p.cur_n   = (int*)alloc((size_t)Nn*4);
  p.cur_c   = (int*)alloc((size_t)NCc*4);
  p.cur_an  = (int*)alloc((size_t)Nn*4);
  p.cur_ac  = (int*)alloc((size_t)NCc*4);
  p.curd_n  = (int*)alloc((size_t)Nn*4);
  p.curd_c  = (int*)alloc((size_t)NCc*4);
  p.maxbits = (u32*)alloc(256);
  p.zcnt = (int*)((char*)p.maxbits + 4);
  p.zbase = (int*)(ws + zstart);
  p.znum = (int)((off - zstart)/4);

  p.xA  = (float*)alloc((size_t)Nn*32*4);
  p.xB  = (float*)alloc((size_t)Nn*32*4);
  p.xC  = (float*)alloc((size_t)Nn*32*4);
  p.cA  = (float*)alloc((size_t)NCc*32*4);
  p.cC0 = (float*)alloc((size_t)NCc*32*4);
  p.m_n = (float*)alloc((size_t)Nn*32*4);
  p.m_c = (float*)alloc((size_t)NCc*32*4);
  p.frn = (float*)alloc((size_t)Nn*32*4);
  p.frc = (float*)alloc((size_t)NCc*32*4);
  p.offs_n  = (int*)alloc((size_t)Nn*4);
  p.offs_c  = (int*)alloc((size_t)NCc*4);
  p.offs_an = (int*)alloc((size_t)Nn*4);
  p.offs_ac = (int*)alloc((size_t)NCc*4);
  p.doffs_n = (int*)alloc((size_t)Nn*4);
  p.doffs_c = (int*)alloc((size_t)NCc*4);
  p.bs0 = (int*)alloc(256); p.bs1 = (int*)alloc(256);
  p.bs2 = (int*)alloc(256); p.bs3 = (int*)alloc(256);
  p.bs4 = (int*)alloc(256); p.bs5 = (int*)alloc(256);
  p.perm_n = (int*)alloc((size_t)Ee*4);
  p.perm_c = (int*)alloc((size_t)ECc*4);
  p.dq_n = (int*)alloc((size_t)Ee*4);
  p.dq_c = (int*)alloc((size_t)ECc*4);
  p.an2c = (int*)alloc((size_t)Aa*4);
  p.ac2n = (int*)alloc((size_t)Aa*4);
  p.sdp_n = (int2*)alloc((size_t)Ee*8);
  p.sdp_c = (int2*)alloc((size_t)ECc*8);
  p.efp_n = (float*)alloc((size_t)Ee*8*4);
  p.efp_c = (float*)alloc((size_t)ECc*8*4);
  p.msg_n = (u32*)alloc((size_t)Ee*16*4);
  p.msg_c = (u32*)alloc((size_t)ECc*16*4);
  p.Wp4 = (u16*)alloc((size_t)4*WPSZ*2);

  int bpc = 0;
  hipOccupancyMaxActiveBlocksPerMultiprocessor(&bpc, k_mega, 512, 0);
  if (bpc < 1) bpc = 1;
  int grid = bpc * 256;
  if (grid > 1563) grid = 1563;

  void* args[] = { &p };
  hipLaunchCooperativeKernel((void*)k_mega, dim3(grid), dim3(512), args, 0, stream);
}

// Round 13
// 355.933 us; speedup vs baseline: 4.2649x; 4.2649x over previous
//
#include <hip/hip_runtime.h>
#include <hip/hip_bf16.h>

typedef unsigned int u32;
typedef unsigned short u16;

#define DEVINL __device__ __forceinline__

constexpr int Nn  = 25000;
constexpr int Ee  = 100000;
constexpr int NCc = 8000;
constexpr int Aa  = 50000;
constexpr int ECc = 24000;
constexpr int TCOLS = 1088;     // 34 k-rows * 32 o-cols
constexpr int WPSZ  = TCOLS*32; // one packed weight set
constexpr int TSP   = 1064;     // LDS T row stride (u16)
constexpr int NB_N = (Nn + 255)/256;   // 98
constexpr int NB_C = (NCc + 255)/256;  // 32

typedef float f32x4 __attribute__((ext_vector_type(4)));
typedef short s16x8 __attribute__((ext_vector_type(8)));

DEVINL float b2f(u16 u){ union{u32 i;float f;}v; v.i = ((u32)u)<<16; return v.f; }
DEVINL float bfl(u32 u){ union{u32 i;float f;}v; v.i = u<<16; return v.f; }
DEVINL float bfh(u32 u){ union{u32 i;float f;}v; v.i = u & 0xffff0000u; return v.f; }
DEVINL u16 f2b(float f){ union{float f;u32 i;}v; v.f=f; u32 i=v.i;
  return (u16)((i + 0x7fffu + ((i>>16)&1u)) >> 16); }
DEVINL u32 pk2(float a, float b){ return (u32)f2b(a) | ((u32)f2b(b) << 16); }
DEVINL float ldw(const void* p, long i, int f){
  return f ? ((const float*)p)[i] : b2f(((const u16*)p)[i]);
}

// ---------- dtype detection + flag (fused via last-block-done) ----------
__global__ __launch_bounds__(256) void k_detect(const u16* __restrict__ p, int n,
                        u32* __restrict__ maxbits, int* __restrict__ zcnt,
                        int* __restrict__ done, int* __restrict__ flag){
  int i0 = blockIdx.x*256 + threadIdx.x;
  float lm = 0.f; int lz = 0;
  for (int i = i0; i < n; i += gridDim.x*256){
    u16 v = p[i];
    if (v == 0) lz++;
    lm = fmaxf(lm, fabsf(b2f(v)));
  }
  #pragma unroll
  for (int off = 32; off; off >>= 1){
    lm = fmaxf(lm, __shfl_down(lm, off));
    lz += __shfl_down(lz, off);
  }
  if ((threadIdx.x & 63) == 0){
    atomicMax(maxbits, __float_as_uint(lm));
    atomicAdd(zcnt, lz);
  }
  __syncthreads();
  if (threadIdx.x == 0){
    __threadfence();
    if (atomicAdd(done, 1) == gridDim.x - 1){
      float m = __uint_as_float(*maxbits);
      *flag = (m > 1e6f || *zcnt > n/4) ? 1 : 0;   // 1 => f32 inputs
    }
  }
}

// ---------- all degree/count histograms ----------
__global__ __launch_bounds__(256) void k_count_all(const int* __restrict__ ei, const int* __restrict__ cei,
                          const int* __restrict__ n2c,
                          int* __restrict__ deg_nd, int* __restrict__ deg_ce,
                          int* __restrict__ deg_n2c, int* __restrict__ deg_c2n,
                          int* __restrict__ cnt_sn, int* __restrict__ cnt_sc){
  int i = blockIdx.x*256 + threadIdx.x;
  if (i < Ee)                             atomicAdd(&deg_nd[ei[Ee + i]], 1);
  else if ((i -= Ee) < ECc)               atomicAdd(&deg_ce[cei[ECc + i]], 1);
  else if ((i -= ECc) < Aa)               atomicAdd(&deg_n2c[n2c[Aa + i]], 1);
  else if ((i -= Aa) < Aa)                atomicAdd(&deg_c2n[n2c[i]], 1);
  else if ((i -= Aa) < Ee)                atomicAdd(&cnt_sn[ei[i]], 1);
  else if ((i -= Ee) < ECc)               atomicAdd(&cnt_sc[cei[i]], 1);
}

// ---------- hierarchical scan over 4 arrays: [cnt_sn(Nn), cnt_sc(NCc), deg_c2n(Nn), deg_n2c(NCc)] ----------
__global__ __launch_bounds__(256) void k_scan_block(
    const int* __restrict__ c0, const int* __restrict__ c1,
    const int* __restrict__ c2, const int* __restrict__ c3,
    int* __restrict__ o0, int* __restrict__ o1, int* __restrict__ o2, int* __restrict__ o3,
    int* __restrict__ b0, int* __restrict__ b1, int* __restrict__ b2, int* __restrict__ b3){
  __shared__ int s[256];
  int bid = blockIdx.x, seg, rb;
  if (bid < NB_N){ seg=0; rb=bid; }
  else if (bid < NB_N+NB_C){ seg=1; rb=bid-NB_N; }
  else if (bid < 2*NB_N+NB_C){ seg=2; rb=bid-NB_N-NB_C; }
  else { seg=3; rb=bid-2*NB_N-NB_C; }
  const int* cnt = seg==0?c0 : seg==1?c1 : seg==2?c2 : c3;
  int* offs = seg==0?o0 : seg==1?o1 : seg==2?o2 : o3;
  int* bs   = seg==0?b0 : seg==1?b1 : seg==2?b2 : b3;
  int M = (seg & 1) ? NCc : Nn;
  int tid = threadIdx.x;
  int i = rb*256 + tid;
  int v = (i < M) ? cnt[i] : 0;
  s[tid] = v; __syncthreads();
  for (int d = 1; d < 256; d <<= 1){
    int t = (tid >= d) ? s[tid-d] : 0;
    __syncthreads();
    s[tid] += t;
    __syncthreads();
  }
  if (i < M) offs[i] = s[tid] - v;
  if (tid == 255) bs[rb] = s[255];
}

__global__ __launch_bounds__(512) void k_spine(int* __restrict__ b0, int* __restrict__ b1,
                      int* __restrict__ b2, int* __restrict__ b3){
  __shared__ int s[512];
  int tid = threadIdx.x, seg = tid >> 7, lane = tid & 127;
  int NB = (seg & 1) ? NB_C : NB_N;
  int* bp = seg==0?b0 : seg==1?b1 : seg==2?b2 : b3;
  int v = (lane < NB) ? bp[lane] : 0;
  s[tid] = v; __syncthreads();
  for (int d = 1; d < 128; d <<= 1){
    int t = (lane >= d) ? s[tid-d] : 0;
    __syncthreads();
    s[tid] += t;
    __syncthreads();
  }
  if (lane < NB) bp[lane] = s[tid] - v;
}

__global__ __launch_bounds__(256) void k_scan_fix(
    int* __restrict__ o0, int* __restrict__ o1, int* __restrict__ o2, int* __restrict__ o3,
    const int* __restrict__ b0, const int* __restrict__ b1,
    const int* __restrict__ b2, const int* __restrict__ b3){
  int i = blockIdx.x*256 + threadIdx.x;
  if (i < Nn) o0[i] += b0[i >> 8];
  else if ((i -= Nn) < NCc) o1[i] += b1[i >> 8];
  else if ((i -= NCc) < Nn) o2[i] += b2[i >> 8];
  else if ((i -= Nn) < NCc) o3[i] += b3[i >> 8];
}

// ---------- place: edge perms + assignment CSRs both directions ----------
__global__ __launch_bounds__(256) void k_place(const int* __restrict__ ei, const int* __restrict__ cei,
                      const int* __restrict__ n2c,
                      const int* __restrict__ offs_n, const int* __restrict__ offs_c,
                      const int* __restrict__ offs_an, const int* __restrict__ offs_ac,
                      int* __restrict__ cur_n, int* __restrict__ cur_c,
                      int* __restrict__ cur_an, int* __restrict__ cur_ac,
                      int* __restrict__ perm_n, int* __restrict__ perm_c,
                      int* __restrict__ an2c, int* __restrict__ ac2n){
  int i = blockIdx.x*256 + threadIdx.x;
  if (i < Ee){
    int s = ei[i];
    perm_n[offs_n[s] + atomicAdd(&cur_n[s], 1)] = i;
  } else if ((i -= Ee) < ECc){
    int s = cei[i];
    perm_c[offs_c[s] + atomicAdd(&cur_c[s], 1)] = i;
  } else if ((i -= ECc) < Aa){
    int c = n2c[Aa + i];   // cid-sorted, payload = nid
    an2c[offs_ac[c] + atomicAdd(&cur_ac[c], 1)] = n2c[i];
  } else if ((i -= Aa) < Aa){
    int nd = n2c[i];       // nid-sorted, payload = cid
    ac2n[offs_an[nd] + atomicAdd(&cur_an[nd], 1)] = n2c[Aa + i];
  }
}

// ---------- gather edge payloads into sorted order ----------
__global__ __launch_bounds__(256) void k_gather(const int* __restrict__ ei, const int* __restrict__ cei,
                       const int* __restrict__ perm_n, const int* __restrict__ perm_c,
                       const void* __restrict__ ef, const void* __restrict__ cef,
                       const int* __restrict__ flag,
                       int2* __restrict__ sdp_n, float* __restrict__ efp_n,
                       int2* __restrict__ sdp_c, float* __restrict__ efp_c){
  int i = blockIdx.x*256 + threadIdx.x;
  int f = *flag;
  if (i < Ee*8){
    int p = i >> 3, j = i & 7;
    int e = perm_n[p];
    efp_n[i] = ldw(ef, (long)e*8 + j, f);
    if (j == 0) sdp_n[p] = make_int2(ei[e], ei[Ee + e]);
  } else if ((i -= Ee*8) < ECc*8){
    int p = i >> 3, j = i & 7;
    int e = perm_c[p];
    efp_c[i] = ldw(cef, (long)e*8 + j, f);
    if (j == 0) sdp_c[p] = make_int2(cei[e], cei[ECc + e]);
  }
}

// ---------- pack all 4 weight sets ----------
__global__ __launch_bounds__(256) void k_wpack_all(const void* __restrict__ nn2w, const void* __restrict__ nn2b,
                          const void* __restrict__ rootw,
                          const void* __restrict__ cnn2w, const void* __restrict__ cnn2b,
                          const void* __restrict__ crootw,
                          const int* __restrict__ flag, u16* __restrict__ Wp4){
  int i = blockIdx.x*256 + threadIdx.x;
  if (i >= 4*WPSZ) return;
  int set = i / WPSZ, j = i - set*WPSZ;
  int l = set >> 1, isC = set & 1;
  const void* W2 = isC ? cnn2w : nn2w;
  const void* B2 = isC ? cnn2b : nn2b;
  const void* RW = isC ? crootw : rootw;
  int f = *flag;
  int col = j >> 5, ii = j & 31;
  float v;
  if (col < 1024)      v = ldw(W2, (long)l*32768 + ((col>>5)<<10) + (ii<<5) + (col&31), f);
  else if (col < 1056) v = ldw(B2, (long)l*1024 + (ii<<5) + (col-1024), f);
  else                 v = ldw(RW, (long)l*1024 + (ii<<5) + (col-1056), f);
  Wp4[i] = f2b(v);
}

// ---------- fused conv (512 threads, R9-winner structure): raw base + folded residual-mean ----------
__global__ __launch_bounds__(512) void k_conv_fused(const void* __restrict__ base, int braw,
                           const float* __restrict__ addagg, const int* __restrict__ adddeg, int M,
                           const int2* __restrict__ sdp, const float* __restrict__ efp,
                           const int* __restrict__ offs, int E_,
                           const void* __restrict__ w1, long w1off,
                           const void* __restrict__ b1, long b1off,
                           const u16* __restrict__ Wp,
                           const void* __restrict__ rb, long rboff,
                           const int* __restrict__ flag,
                           float* __restrict__ feat_root, float* __restrict__ agg){
  __shared__ __align__(16) u16 Ts[16*TSP];
  __shared__ float w1s[256];
  __shared__ __align__(8) u32 hws[8][4][16];
  int tid = threadIdx.x;
  int w = tid >> 6, lane = tid & 63;
  int quad = lane >> 4, lm = lane & 15;
  int n0 = blockIdx.x * 16;
  int f = *flag;
  int bf = braw ? f : 1;
  if (tid < 256) w1s[tid] = ldw(w1, w1off + tid, f);
  float bb0 = ldw(b1, b1off + 2*lm, f);
  float bb1 = ldw(b1, b1off + 2*lm + 1, f);
  // x fragment for the 16 window nodes (residual-mean folded)
  int n = n0 + lm;
  int nc = n < M ? n : M-1;
  long bidx = (long)nc*32 + quad*8;
  float fv[8];
  #pragma unroll
  for (int j = 0; j < 8; j++) fv[j] = ldw(base, bidx + j, bf);
  if (addagg){
    int dg = adddeg[nc];
    float d = (float)(dg > 1 ? dg : 1);
    const float* ap = addagg + (size_t)nc*32 + quad*8;
    #pragma unroll
    for (int j = 0; j < 8; j++) fv[j] += ap[j]/d;
  }
  s16x8 bfrag;
  #pragma unroll
  for (int j = 0; j < 8; j++) bfrag[j] = (short)f2b(fv[j]);
  // phase 1: wave w handles col-tiles [9w, 9w+9) of 68
  #pragma unroll 1
  for (int ti = 0; ti < 9; ti++){
    int ct = w*9 + ti;
    if (ct >= 68) break;
    int colbase = ct*16;
    s16x8 afrag = *(const s16x8*)(Wp + (size_t)(colbase + lm)*32 + quad*8);
    f32x4 acc = {0.f, 0.f, 0.f, 0.f};
    acc = __builtin_amdgcn_mfma_f32_16x16x32_bf16(afrag, bfrag, acc, 0, 0, 0);
    int cb = colbase + quad*4;
    if (ct < 66){
      u32 lo = (u32)f2b(acc[0]) | ((u32)f2b(acc[1]) << 16);
      u32 hi = (u32)f2b(acc[2]) | ((u32)f2b(acc[3]) << 16);
      *(uint2*)&Ts[lm*TSP + cb] = make_uint2(lo, hi);
    } else if (n < M){
      int o = cb - 1056;
      float4 v = make_float4(acc[0] + ldw(rb, rboff+o,   f),
                             acc[1] + ldw(rb, rboff+o+1, f),
                             acc[2] + ldw(rb, rboff+o+2, f),
                             acc[3] + ldw(rb, rboff+o+3, f));
      *(float4*)&feat_root[(size_t)n*32 + o] = v;
    }
  }
  __syncthreads();
  // phase 2: streaming edges, 4/wave-iter across 8 waves, register prefetch
  int lo = offs[n0];
  int hi = (n0 + 16 < M) ? offs[n0 + 16] : E_;
  int eg = quad, kk = lm;
  int pos = lo + w*4;
  float efv = 0.f; int sdv = 0;
  if (lane < 32){ int idx = pos*8 + lane; if (idx < hi*8) efv = efp[idx]; }
  else if (lane < 40){ int idx = pos*2 + (lane-32); if (idx < hi*2) sdv = ((const int*)sdp)[idx]; }
  for (; pos < hi; pos += 32){
    int np = pos + 32;
    float efv_n = 0.f; int sdv_n = 0;
    if (lane < 32){ int idx = np*8 + lane; if (idx < hi*8) efv_n = efp[idx]; }
    else if (lane < 40){ int idx = np*2 + (lane-32); if (idx < hi*2) sdv_n = ((const int*)sdp)[idx]; }
    int sn = __shfl(sdv, 32 + 2*eg);
    int dn = __shfl(sdv, 33 + 2*eg);
    bool valid = (pos + eg < hi);
    int sr = sn - n0; sr = sr < 0 ? 0 : (sr > 15 ? 15 : sr);
    // edge MLP (h), packed to bf16 pair
    float a0 = bb0, a1 = bb1;
    #pragma unroll
    for (int j = 0; j < 8; j++){
      float ev = __shfl(efv, eg*8 + j);
      a0 += ev * w1s[j*32 + 2*kk];
      a1 += ev * w1s[j*32 + 2*kk+1];
    }
    hws[w][eg][kk] = pk2(fmaxf(a0, 0.f), fmaxf(a1, 0.f));
    if (valid){
      const u16* Tr = &Ts[sr*TSP];
      u32 vb = *(const u32*)&Tr[1024 + 2*kk];   // b2 row (h=1)
      float m0 = bfl(vb), m1 = bfh(vb);
      #pragma unroll
      for (int kq = 0; kq < 16; kq++){
        u32 hp = hws[w][eg][kq];
        float h0 = bfl(hp), h1 = bfh(hp);
        u32 v0 = *(const u32*)&Tr[(2*kq)*32 + 2*kk];
        u32 v1 = *(const u32*)&Tr[(2*kq+1)*32 + 2*kk];
        m0 += h0*bfl(v0) + h1*bfl(v1);
        m1 += h0*bfh(v0) + h1*bfh(v1);
      }
      float* ap = agg + (size_t)dn*32 + 2*kk;
      atomicAdd(ap,   m0);
      atomicAdd(ap+1, m1);
    }
    efv = efv_n; sdv = sdv_n;
  }
}

// ---------- fused: feat = relu(agg/deg + froot); m = feat@w+b; scatter m into sagg ----------
__global__ __launch_bounds__(256) void k_update_lin(const float* __restrict__ agg, const int* __restrict__ deg,
                           const float* __restrict__ feat_root, int M,
                           const void* __restrict__ w, long woff,
                           const void* __restrict__ b, long boff,
                           const int* __restrict__ flag,
                           float* __restrict__ feat,
                           const int* __restrict__ sidx, const int* __restrict__ soffs,
                           const int* __restrict__ sdeg, float* __restrict__ sagg){
  __shared__ float wsm[1024], bs[32], rows[8][33];
  int tid = threadIdx.x;
  int f = *flag;
  for (int idx = tid; idx < 1024; idx += 256) wsm[idx] = ldw(w, woff + idx, f);
  if (tid < 32) bs[tid] = ldw(b, boff + tid, f);
  int nl = tid >> 5, o = tid & 31;
  int n = blockIdx.x*8 + nl;
  long i = (long)n*32 + o;
  if (n < M){
    int dg = deg[n];
    float d = (float)(dg > 1 ? dg : 1);
    float v = fmaxf(agg[i]/d + feat_root[i], 0.f);
    rows[nl][o] = v;
    feat[i] = v;
  }
  __syncthreads();
  if (n >= M) return;
  float acc = bs[o];
  #pragma unroll
  for (int j = 0; j < 32; j++) acc += rows[nl][j]*wsm[j*32+o];
  // fused scatter: add m to each assignment target
  int slo = soffs[n], scnt = sdeg[n];
  for (int a = 0; a < scnt; a++)
    atomicAdd(&sagg[(size_t)sidx[slo + a]*32 + o], acc);
}

// ---------- final store: x = xC + aggS1/deg, c = cC1 ----------
__global__ __launch_bounds__(256) void k_store(const float* __restrict__ x, const float* __restrict__ xagg,
                      const int* __restrict__ xdeg, const float* __restrict__ c,
                      void* __restrict__ out, const int* __restrict__ flag){
  int i = blockIdx.x*256 + threadIdx.x;
  int tot = Nn*32 + NCc*32;
  if (i >= tot) return;
  float v;
  if (i < Nn*32){
    int n = i >> 5;
    int dg = xdeg[n];
    float d = (float)(dg > 1 ? dg : 1);
    v = x[i] + xagg[i]/d;
  } else v = c[i - Nn*32];
  if (*flag) ((float*)out)[i] = v;
  else       ((u16*)out)[i]   = f2b(v);
}

extern "C" void kernel_launch(void* const* d_in, const int* in_sizes, int n_in,
                              void* d_out, int out_size, void* d_ws, size_t ws_size,
                              hipStream_t stream){
  const int* ei  = (const int*)d_in[1];
  const int* n2c = (const int*)d_in[4];
  const int* cei = (const int*)d_in[5];
  const void *efr = d_in[2], *cefr = d_in[6];
  const void *nn1w = d_in[7], *nn1b = d_in[8], *nn2w = d_in[9], *nn2b = d_in[10],
             *rootw = d_in[11], *rootb = d_in[12], *n2cw = d_in[13], *n2cb = d_in[14],
             *cnn1w = d_in[15], *cnn1b = d_in[16], *cnn2w = d_in[17], *cnn2b = d_in[18],
             *crootw = d_in[19], *crootb = d_in[20], *c2nw = d_in[21], *c2nb = d_in[22];

  char* ws = (char*)d_ws;
  size_t off = 0;
  auto alloc = [&](size_t bytes){ void* p = ws + off; off += (bytes + 255) & ~(size_t)255; return p; };

  // ---- zeroed region (single memset) ----
  size_t zstart = off;
  float* aggE0  = (float*)alloc((size_t)Nn*32*4);
  float* aggE1  = (float*)alloc((size_t)Nn*32*4);
  float* caggE0 = (float*)alloc((size_t)NCc*32*4);
  float* caggE1 = (float*)alloc((size_t)NCc*32*4);
  float* caggS0 = (float*)alloc((size_t)NCc*32*4);
  float* caggS1 = (float*)alloc((size_t)NCc*32*4);
  float* aggS0  = (float*)alloc((size_t)Nn*32*4);
  float* aggS1  = (float*)alloc((size_t)Nn*32*4);
  int* deg_nd  = (int*)alloc((size_t)Nn*4);
  int* deg_ce  = (int*)alloc((size_t)NCc*4);
  int* deg_n2c = (int*)alloc((size_t)NCc*4);
  int* deg_c2n = (int*)alloc((size_t)Nn*4);
  int* cnt_sn  = (int*)alloc((size_t)Nn*4);
  int* cnt_sc  = (int*)alloc((size_t)NCc*4);
  int* cur_n   = (int*)alloc((size_t)Nn*4);
  int* cur_c   = (int*)alloc((size_t)NCc*4);
  int* cur_an  = (int*)alloc((size_t)Nn*4);
  int* cur_ac  = (int*)alloc((size_t)NCc*4);
  u32* maxbits = (u32*)alloc(256);
  int* zcnt = (int*)((char*)maxbits + 4);
  int* flag = (int*)((char*)maxbits + 8);
  int* done = (int*)((char*)maxbits + 12);
  size_t zbytes = off - zstart;

  // ---- non-zeroed ----
  float* xB  = (float*)alloc((size_t)Nn*32*4);
  float* xC  = (float*)alloc((size_t)Nn*32*4);
  float* cC0 = (float*)alloc((size_t)NCc*32*4);
  float* cC1 = (float*)alloc((size_t)NCc*32*4);
  float* frn = (float*)alloc((size_t)Nn*32*4);
  float* frc = (float*)alloc((size_t)NCc*32*4);
  int* offs_n  = (int*)alloc((size_t)Nn*4);
  int* offs_c  = (int*)alloc((size_t)NCc*4);
  int* offs_an = (int*)alloc((size_t)Nn*4);
  int* offs_ac = (int*)alloc((size_t)NCc*4);
  int* bs0 = (int*)alloc(512); int* bs1 = (int*)alloc(512);
  int* bs2 = (int*)alloc(512); int* bs3 = (int*)alloc(512);
  int* perm_n = (int*)alloc((size_t)Ee*4);
  int* perm_c = (int*)alloc((size_t)ECc*4);
  int* an2c = (int*)alloc((size_t)Aa*4);
  int* ac2n = (int*)alloc((size_t)Aa*4);
  int2* sdp_n = (int2*)alloc((size_t)Ee*8);
  int2* sdp_c = (int2*)alloc((size_t)ECc*8);
  float* efp_n = (float*)alloc((size_t)Ee*8*4);
  float* efp_c = (float*)alloc((size_t)ECc*8*4);
  u16* Wp4 = (u16*)alloc((size_t)4*WPSZ*2);

  auto nb = [](int n){ return (n + 255)/256; };

  // 1. memset accumulators/counters
  hipMemsetAsync(ws + zstart, 0, zbytes, stream);
  // 2. dtype detect
  k_detect<<<256,256,0,stream>>>((const u16*)d_in[0], Nn*32, maxbits, zcnt, done, flag);
  // 3. histograms + 4-way scan + counting sorts + payload gather
  k_count_all<<<nb(2*Ee + 2*ECc + 2*Aa),256,0,stream>>>(ei, cei, n2c,
      deg_nd, deg_ce, deg_n2c, deg_c2n, cnt_sn, cnt_sc);
  k_scan_block<<<2*(NB_N+NB_C),256,0,stream>>>(cnt_sn, cnt_sc, deg_c2n, deg_n2c,
      offs_n, offs_c, offs_an, offs_ac, bs0, bs1, bs2, bs3);
  k_spine<<<1,512,0,stream>>>(bs0, bs1, bs2, bs3);
  k_scan_fix<<<nb(2*(Nn+NCc)),256,0,stream>>>(offs_n, offs_c, offs_an, offs_ac,
      bs0, bs1, bs2, bs3);
  k_place<<<nb(Ee+ECc+2*Aa),256,0,stream>>>(ei, cei, n2c, offs_n, offs_c, offs_an, offs_ac,
      cur_n, cur_c, cur_an, cur_ac, perm_n, perm_c, an2c, ac2n);
  k_gather<<<nb(8*(Ee+ECc)),256,0,stream>>>(ei, cei, perm_n, perm_c, efr, cefr, flag,
      sdp_n, efp_n, sdp_c, efp_c);
  // 4. pack weights
  k_wpack_all<<<nb(4*WPSZ),256,0,stream>>>(nn2w, nn2b, rootw, cnn2w, cnn2b, crootw, flag, Wp4);

  int Gn = (Nn + 15)/16, Gc = (NCc + 15)/16;

  // ---- layer 0 ----
  k_conv_fused<<<Gn,512,0,stream>>>(d_in[0], 1, nullptr, nullptr, Nn, sdp_n, efp_n, offs_n, Ee,
      nn1w, 0, nn1b, 0, Wp4 + 0*WPSZ, rootb, 0, flag, frn, aggE0);
  k_update_lin<<<(Nn+7)/8,256,0,stream>>>(aggE0, deg_nd, frn, Nn, n2cw, 0, n2cb, 0, flag,
      xB, ac2n, offs_an, deg_c2n, caggS0);
  k_conv_fused<<<Gc,512,0,stream>>>(d_in[3], 1, caggS0, deg_n2c, NCc, sdp_c, efp_c, offs_c, ECc,
      cnn1w, 0, cnn1b, 0, Wp4 + 1*WPSZ, crootb, 0, flag, frc, caggE0);
  k_update_lin<<<(NCc+7)/8,256,0,stream>>>(caggE0, deg_ce, frc, NCc, c2nw, 0, c2nb, 0, flag,
      cC0, an2c, offs_ac, deg_n2c, aggS0);
  // ---- layer 1 ----
  k_conv_fused<<<Gn,512,0,stream>>>(xB, 0, aggS0, deg_c2n, Nn, sdp_n, efp_n, offs_n, Ee,
      nn1w, 256, nn1b, 32, Wp4 + 2*WPSZ, rootb, 32, flag, frn, aggE1);
  k_update_lin<<<(Nn+7)/8,256,0,stream>>>(aggE1, deg_nd, frn, Nn, n2cw, 1024, n2cb, 32, flag,
      xC, ac2n, offs_an, deg_c2n, caggS1);
  k_conv_fused<<<Gc,512,0,stream>>>(cC0, 0, caggS1, deg_n2c, NCc, sdp_c, efp_c, offs_c, ECc,
      cnn1w, 256, cnn1b, 32, Wp4 + 3*WPSZ, crootb, 32, flag, frc, caggE1);
  k_update_lin<<<(NCc+7)/8,256,0,stream>>>(caggE1, deg_ce, frc, NCc, c2nw, 1024, c2nb, 32, flag,
      cC1, an2c, offs_ac, deg_n2c, aggS1);
  // ---- output ----
  k_store<<<nb(Nn*32 + NCc*32),256,0,stream>>>(xC, aggS1, deg_c2n, cC1, d_out, flag);
}

// Round 14
// 343.048 us; speedup vs baseline: 4.4251x; 1.0376x over previous
//
#include <hip/hip_runtime.h>
#include <hip/hip_bf16.h>

typedef unsigned int u32;
typedef unsigned short u16;

#define DEVINL __device__ __forceinline__

constexpr int Nn  = 25000;
constexpr int Ee  = 100000;
constexpr int NCc = 8000;
constexpr int Aa  = 50000;
constexpr int ECc = 24000;
constexpr int TCOLS = 1088;     // 34 k-rows * 32 o-cols
constexpr int WPSZ  = TCOLS*32; // one packed weight set
constexpr int TSP   = 1064;     // LDS T row stride (u16)
constexpr int NB_N = (Nn + 255)/256;   // 98
constexpr int NB_C = (NCc + 255)/256;  // 32

typedef float f32x4 __attribute__((ext_vector_type(4)));
typedef short s16x8 __attribute__((ext_vector_type(8)));

DEVINL float b2f(u16 u){ union{u32 i;float f;}v; v.i = ((u32)u)<<16; return v.f; }
DEVINL float bfl(u32 u){ union{u32 i;float f;}v; v.i = u<<16; return v.f; }
DEVINL float bfh(u32 u){ union{u32 i;float f;}v; v.i = u & 0xffff0000u; return v.f; }
DEVINL u16 f2b(float f){ union{float f;u32 i;}v; v.f=f; u32 i=v.i;
  return (u16)((i + 0x7fffu + ((i>>16)&1u)) >> 16); }
DEVINL u32 pk2(float a, float b){ return (u32)f2b(a) | ((u32)f2b(b) << 16); }
DEVINL float ldw(const void* p, long i, int f){
  return f ? ((const float*)p)[i] : b2f(((const u16*)p)[i]);
}

// ---------- dtype detection + flag (fused via last-block-done) ----------
__global__ __launch_bounds__(256) void k_detect(const u16* __restrict__ p, int n,
                        u32* __restrict__ maxbits, int* __restrict__ zcnt,
                        int* __restrict__ done, int* __restrict__ flag){
  int i0 = blockIdx.x*256 + threadIdx.x;
  float lm = 0.f; int lz = 0;
  for (int i = i0; i < n; i += gridDim.x*256){
    u16 v = p[i];
    if (v == 0) lz++;
    lm = fmaxf(lm, fabsf(b2f(v)));
  }
  #pragma unroll
  for (int off = 32; off; off >>= 1){
    lm = fmaxf(lm, __shfl_down(lm, off));
    lz += __shfl_down(lz, off);
  }
  if ((threadIdx.x & 63) == 0){
    atomicMax(maxbits, __float_as_uint(lm));
    atomicAdd(zcnt, lz);
  }
  __syncthreads();
  if (threadIdx.x == 0){
    __threadfence();
    if (atomicAdd(done, 1) == gridDim.x - 1){
      float m = __uint_as_float(*maxbits);
      *flag = (m > 1e6f || *zcnt > n/4) ? 1 : 0;   // 1 => f32 inputs
    }
  }
}

// ---------- all degree/count histograms ----------
__global__ __launch_bounds__(256) void k_count_all(const int* __restrict__ ei, const int* __restrict__ cei,
                          const int* __restrict__ n2c,
                          int* __restrict__ deg_nd, int* __restrict__ deg_ce,
                          int* __restrict__ deg_n2c, int* __restrict__ deg_c2n,
                          int* __restrict__ cnt_sn, int* __restrict__ cnt_sc){
  int i = blockIdx.x*256 + threadIdx.x;
  if (i < Ee)                             atomicAdd(&deg_nd[ei[Ee + i]], 1);
  else if ((i -= Ee) < ECc)               atomicAdd(&deg_ce[cei[ECc + i]], 1);
  else if ((i -= ECc) < Aa)               atomicAdd(&deg_n2c[n2c[Aa + i]], 1);
  else if ((i -= Aa) < Aa)                atomicAdd(&deg_c2n[n2c[i]], 1);
  else if ((i -= Aa) < Ee)                atomicAdd(&cnt_sn[ei[i]], 1);
  else if ((i -= Ee) < ECc)               atomicAdd(&cnt_sc[cei[i]], 1);
}

// ---------- hierarchical scan over 4 arrays ----------
__global__ __launch_bounds__(256) void k_scan_block(
    const int* __restrict__ c0, const int* __restrict__ c1,
    const int* __restrict__ c2, const int* __restrict__ c3,
    int* __restrict__ o0, int* __restrict__ o1, int* __restrict__ o2, int* __restrict__ o3,
    int* __restrict__ b0, int* __restrict__ b1, int* __restrict__ b2, int* __restrict__ b3){
  __shared__ int s[256];
  int bid = blockIdx.x, seg, rb;
  if (bid < NB_N){ seg=0; rb=bid; }
  else if (bid < NB_N+NB_C){ seg=1; rb=bid-NB_N; }
  else if (bid < 2*NB_N+NB_C){ seg=2; rb=bid-NB_N-NB_C; }
  else { seg=3; rb=bid-2*NB_N-NB_C; }
  const int* cnt = seg==0?c0 : seg==1?c1 : seg==2?c2 : c3;
  int* offs = seg==0?o0 : seg==1?o1 : seg==2?o2 : o3;
  int* bs   = seg==0?b0 : seg==1?b1 : seg==2?b2 : b3;
  int M = (seg & 1) ? NCc : Nn;
  int tid = threadIdx.x;
  int i = rb*256 + tid;
  int v = (i < M) ? cnt[i] : 0;
  s[tid] = v; __syncthreads();
  for (int d = 1; d < 256; d <<= 1){
    int t = (tid >= d) ? s[tid-d] : 0;
    __syncthreads();
    s[tid] += t;
    __syncthreads();
  }
  if (i < M) offs[i] = s[tid] - v;
  if (tid == 255) bs[rb] = s[255];
}

__global__ __launch_bounds__(512) void k_spine(int* __restrict__ b0, int* __restrict__ b1,
                      int* __restrict__ b2, int* __restrict__ b3){
  __shared__ int s[512];
  int tid = threadIdx.x, seg = tid >> 7, lane = tid & 127;
  int NB = (seg & 1) ? NB_C : NB_N;
  int* bp = seg==0?b0 : seg==1?b1 : seg==2?b2 : b3;
  int v = (lane < NB) ? bp[lane] : 0;
  s[tid] = v; __syncthreads();
  for (int d = 1; d < 128; d <<= 1){
    int t = (lane >= d) ? s[tid-d] : 0;
    __syncthreads();
    s[tid] += t;
    __syncthreads();
  }
  if (lane < NB) bp[lane] = s[tid] - v;
}

__global__ __launch_bounds__(256) void k_scan_fix(
    int* __restrict__ o0, int* __restrict__ o1, int* __restrict__ o2, int* __restrict__ o3,
    const int* __restrict__ b0, const int* __restrict__ b1,
    const int* __restrict__ b2, const int* __restrict__ b3){
  int i = blockIdx.x*256 + threadIdx.x;
  if (i < Nn) o0[i] += b0[i >> 8];
  else if ((i -= Nn) < NCc) o1[i] += b1[i >> 8];
  else if ((i -= NCc) < Nn) o2[i] += b2[i >> 8];
  else if ((i -= Nn) < NCc) o3[i] += b3[i >> 8];
}

// ---------- place: edge perms + assignment CSRs ----------
__global__ __launch_bounds__(256) void k_place(const int* __restrict__ ei, const int* __restrict__ cei,
                      const int* __restrict__ n2c,
                      const int* __restrict__ offs_n, const int* __restrict__ offs_c,
                      const int* __restrict__ offs_an, const int* __restrict__ offs_ac,
                      int* __restrict__ cur_n, int* __restrict__ cur_c,
                      int* __restrict__ cur_an, int* __restrict__ cur_ac,
                      int* __restrict__ perm_n, int* __restrict__ perm_c,
                      int* __restrict__ an2c, int* __restrict__ ac2n){
  int i = blockIdx.x*256 + threadIdx.x;
  if (i < Ee){
    int s = ei[i];
    perm_n[offs_n[s] + atomicAdd(&cur_n[s], 1)] = i;
  } else if ((i -= Ee) < ECc){
    int s = cei[i];
    perm_c[offs_c[s] + atomicAdd(&cur_c[s], 1)] = i;
  } else if ((i -= ECc) < Aa){
    int c = n2c[Aa + i];
    an2c[offs_ac[c] + atomicAdd(&cur_ac[c], 1)] = n2c[i];
  } else if ((i -= Aa) < Aa){
    int nd = n2c[i];
    ac2n[offs_an[nd] + atomicAdd(&cur_an[nd], 1)] = n2c[Aa + i];
  }
}

// ---------- gather edge payloads into sorted order ----------
__global__ __launch_bounds__(256) void k_gather(const int* __restrict__ ei, const int* __restrict__ cei,
                       const int* __restrict__ perm_n, const int* __restrict__ perm_c,
                       const void* __restrict__ ef, const void* __restrict__ cef,
                       const int* __restrict__ flag,
                       int2* __restrict__ sdp_n, float* __restrict__ efp_n,
                       int2* __restrict__ sdp_c, float* __restrict__ efp_c){
  int i = blockIdx.x*256 + threadIdx.x;
  int f = *flag;
  if (i < Ee*8){
    int p = i >> 3, j = i & 7;
    int e = perm_n[p];
    efp_n[i] = ldw(ef, (long)e*8 + j, f);
    if (j == 0) sdp_n[p] = make_int2(ei[e], ei[Ee + e]);
  } else if ((i -= Ee*8) < ECc*8){
    int p = i >> 3, j = i & 7;
    int e = perm_c[p];
    efp_c[i] = ldw(cef, (long)e*8 + j, f);
    if (j == 0) sdp_c[p] = make_int2(cei[e], cei[ECc + e]);
  }
}

// ---------- pack all 4 weight sets ----------
__global__ __launch_bounds__(256) void k_wpack_all(const void* __restrict__ nn2w, const void* __restrict__ nn2b,
                          const void* __restrict__ rootw,
                          const void* __restrict__ cnn2w, const void* __restrict__ cnn2b,
                          const void* __restrict__ crootw,
                          const int* __restrict__ flag, u16* __restrict__ Wp4){
  int i = blockIdx.x*256 + threadIdx.x;
  if (i >= 4*WPSZ) return;
  int set = i / WPSZ, j = i - set*WPSZ;
  int l = set >> 1, isC = set & 1;
  const void* W2 = isC ? cnn2w : nn2w;
  const void* B2 = isC ? cnn2b : nn2b;
  const void* RW = isC ? crootw : rootw;
  int f = *flag;
  int col = j >> 5, ii = j & 31;
  float v;
  if (col < 1024)      v = ldw(W2, (long)l*32768 + ((col>>5)<<10) + (ii<<5) + (col&31), f);
  else if (col < 1056) v = ldw(B2, (long)l*1024 + (ii<<5) + (col-1024), f);
  else                 v = ldw(RW, (long)l*1024 + (ii<<5) + (col-1056), f);
  Wp4[i] = f2b(v);
}

// ---------- fused conv: vectorized raw-base read + MFMA T + streaming edges (depth-2) ----------
__global__ __launch_bounds__(512) void k_conv_fused(const void* __restrict__ base, int braw,
                           const float* __restrict__ addagg, const int* __restrict__ adddeg, int M,
                           const int2* __restrict__ sdp, const float* __restrict__ efp,
                           const int* __restrict__ offs, int E_,
                           const void* __restrict__ w1, long w1off,
                           const void* __restrict__ b1, long b1off,
                           const u16* __restrict__ Wp,
                           const void* __restrict__ rb, long rboff,
                           const int* __restrict__ flag,
                           float* __restrict__ feat_root, float* __restrict__ agg){
  __shared__ __align__(16) u16 Ts[16*TSP];
  __shared__ float w1s[256];
  __shared__ __align__(8) u32 hws[8][4][16];
  int tid = threadIdx.x;
  int w = tid >> 6, lane = tid & 63;
  int quad = lane >> 4, lm = lane & 15;
  int n0 = blockIdx.x * 16;
  int f = *flag;
  if (tid < 256) w1s[tid] = ldw(w1, w1off + tid, f);
  float bb0 = ldw(b1, b1off + 2*lm, f);
  float bb1 = ldw(b1, b1off + 2*lm + 1, f);
  // x fragment: vectorized loads on both dtype paths
  int n = n0 + lm;
  int nc = n < M ? n : M-1;
  long bidx = (long)nc*32 + quad*8;
  float fv[8];
  if (braw && f == 0){
    uint4 q = *(const uint4*)((const u16*)base + bidx);
    fv[0]=bfl(q.x); fv[1]=bfh(q.x); fv[2]=bfl(q.y); fv[3]=bfh(q.y);
    fv[4]=bfl(q.z); fv[5]=bfh(q.z); fv[6]=bfl(q.w); fv[7]=bfh(q.w);
  } else {
    const float4* bp = (const float4*)((const float*)base + bidx);
    float4 q0 = bp[0], q1 = bp[1];
    fv[0]=q0.x; fv[1]=q0.y; fv[2]=q0.z; fv[3]=q0.w;
    fv[4]=q1.x; fv[5]=q1.y; fv[6]=q1.z; fv[7]=q1.w;
  }
  if (addagg){
    int dg = adddeg[nc];
    float d = (float)(dg > 1 ? dg : 1);
    const float4* ap = (const float4*)(addagg + (size_t)nc*32 + quad*8);
    float4 a0 = ap[0], a1 = ap[1];
    float inv = 1.f/d;
    fv[0]+=a0.x*inv; fv[1]+=a0.y*inv; fv[2]+=a0.z*inv; fv[3]+=a0.w*inv;
    fv[4]+=a1.x*inv; fv[5]+=a1.y*inv; fv[6]+=a1.z*inv; fv[7]+=a1.w*inv;
  }
  s16x8 bfrag;
  #pragma unroll
  for (int j = 0; j < 8; j++) bfrag[j] = (short)f2b(fv[j]);
  // phase 1: wave w handles col-tiles [9w, 9w+9) of 68
  #pragma unroll 1
  for (int ti = 0; ti < 9; ti++){
    int ct = w*9 + ti;
    if (ct >= 68) break;
    int colbase = ct*16;
    s16x8 afrag = *(const s16x8*)(Wp + (size_t)(colbase + lm)*32 + quad*8);
    f32x4 acc = {0.f, 0.f, 0.f, 0.f};
    acc = __builtin_amdgcn_mfma_f32_16x16x32_bf16(afrag, bfrag, acc, 0, 0, 0);
    int cb = colbase + quad*4;
    if (ct < 66){
      u32 lo = (u32)f2b(acc[0]) | ((u32)f2b(acc[1]) << 16);
      u32 hi = (u32)f2b(acc[2]) | ((u32)f2b(acc[3]) << 16);
      *(uint2*)&Ts[lm*TSP + cb] = make_uint2(lo, hi);
    } else if (n < M){
      int o = cb - 1056;
      float4 v = make_float4(acc[0] + ldw(rb, rboff+o,   f),
                             acc[1] + ldw(rb, rboff+o+1, f),
                             acc[2] + ldw(rb, rboff+o+2, f),
                             acc[3] + ldw(rb, rboff+o+3, f));
      *(float4*)&feat_root[(size_t)n*32 + o] = v;
    }
  }
  __syncthreads();
  // phase 2: streaming edges, 4/wave-iter, depth-2 prefetch
  int lo = offs[n0];
  int hi = (n0 + 16 < M) ? offs[n0 + 16] : E_;
  int eg = quad, kk = lm;
  int pos = lo + w*4;
  float ef0 = 0.f, ef1 = 0.f; int sd0 = 0, sd1 = 0;
  if (lane < 32){
    int idx = pos*8 + lane;        if (idx < hi*8) ef0 = efp[idx];
    idx = (pos+32)*8 + lane;       if (idx < hi*8) ef1 = efp[idx];
  } else if (lane < 40){
    int idx = pos*2 + (lane-32);   if (idx < hi*2) sd0 = ((const int*)sdp)[idx];
    idx = (pos+32)*2 + (lane-32);  if (idx < hi*2) sd1 = ((const int*)sdp)[idx];
  }
  for (; pos < hi; pos += 32){
    int np = pos + 64;
    float ef2 = 0.f; int sd2 = 0;
    if (lane < 32){ int idx = np*8 + lane; if (idx < hi*8) ef2 = efp[idx]; }
    else if (lane < 40){ int idx = np*2 + (lane-32); if (idx < hi*2) sd2 = ((const int*)sdp)[idx]; }
    int sn = __shfl(sd0, 32 + 2*eg);
    int dn = __shfl(sd0, 33 + 2*eg);
    bool valid = (pos + eg < hi);
    int sr = sn - n0; sr = sr < 0 ? 0 : (sr > 15 ? 15 : sr);
    float a0 = bb0, a1 = bb1;
    #pragma unroll
    for (int j = 0; j < 8; j++){
      float ev = __shfl(ef0, eg*8 + j);
      a0 += ev * w1s[j*32 + 2*kk];
      a1 += ev * w1s[j*32 + 2*kk+1];
    }
    hws[w][eg][kk] = pk2(fmaxf(a0, 0.f), fmaxf(a1, 0.f));
    if (valid){
      const u16* Tr = &Ts[sr*TSP];
      u32 vb = *(const u32*)&Tr[1024 + 2*kk];   // b2 row (h=1)
      float m0 = bfl(vb), m1 = bfh(vb);
      #pragma unroll
      for (int kq = 0; kq < 16; kq++){
        u32 hp = hws[w][eg][kq];
        float h0 = bfl(hp), h1 = bfh(hp);
        u32 v0 = *(const u32*)&Tr[(2*kq)*32 + 2*kk];
        u32 v1 = *(const u32*)&Tr[(2*kq+1)*32 + 2*kk];
        m0 += h0*bfl(v0) + h1*bfl(v1);
        m1 += h0*bfh(v0) + h1*bfh(v1);
      }
      float* ap = agg + (size_t)dn*32 + 2*kk;
      atomicAdd(ap,   m0);
      atomicAdd(ap+1, m1);
    }
    ef0 = ef1; sd0 = sd1; ef1 = ef2; sd1 = sd2;
  }
}

// ---------- fused: feat = relu(agg/deg + froot); m = feat@w+b; scatter m into sagg ----------
__global__ __launch_bounds__(256) void k_update_lin(const float* __restrict__ agg, const int* __restrict__ deg,
                           const float* __restrict__ feat_root, int M,
                           const void* __restrict__ w, long woff,
                           const void* __restrict__ b, long boff,
                           const int* __restrict__ flag,
                           float* __restrict__ feat,
                           const int* __restrict__ sidx, const int* __restrict__ soffs,
                           const int* __restrict__ sdeg, float* __restrict__ sagg){
  __shared__ float wsm[1024], bs[32], rows[8][33];
  int tid = threadIdx.x;
  int f = *flag;
  for (int idx = tid; idx < 1024; idx += 256) wsm[idx] = ldw(w, woff + idx, f);
  if (tid < 32) bs[tid] = ldw(b, boff + tid, f);
  int nl = tid >> 5, o = tid & 31;
  int n = blockIdx.x*8 + nl;
  long i = (long)n*32 + o;
  if (n < M){
    int dg = deg[n];
    float d = (float)(dg > 1 ? dg : 1);
    float v = fmaxf(agg[i]/d + feat_root[i], 0.f);
    rows[nl][o] = v;
    feat[i] = v;
  }
  __syncthreads();
  if (n >= M) return;
  float acc = bs[o];
  #pragma unroll
  for (int j = 0; j < 32; j++) acc += rows[nl][j]*wsm[j*32+o];
  int slo = soffs[n], scnt = sdeg[n];
  for (int a = 0; a < scnt; a++)
    atomicAdd(&sagg[(size_t)sidx[slo + a]*32 + o], acc);
}

// ---------- final store ----------
__global__ __launch_bounds__(256) void k_store(const float* __restrict__ x, const float* __restrict__ xagg,
                      const int* __restrict__ xdeg, const float* __restrict__ c,
                      void* __restrict__ out, const int* __restrict__ flag){
  int i = blockIdx.x*256 + threadIdx.x;
  int tot = Nn*32 + NCc*32;
  if (i >= tot) return;
  float v;
  if (i < Nn*32){
    int n = i >> 5;
    int dg = xdeg[n];
    float d = (float)(dg > 1 ? dg : 1);
    v = x[i] + xagg[i]/d;
  } else v = c[i - Nn*32];
  if (*flag) ((float*)out)[i] = v;
  else       ((u16*)out)[i]   = f2b(v);
}

extern "C" void kernel_launch(void* const* d_in, const int* in_sizes, int n_in,
                              void* d_out, int out_size, void* d_ws, size_t ws_size,
                              hipStream_t stream){
  const int* ei  = (const int*)d_in[1];
  const int* n2c = (const int*)d_in[4];
  const int* cei = (const int*)d_in[5];
  const void *efr = d_in[2], *cefr = d_in[6];
  const void *nn1w = d_in[7], *nn1b = d_in[8], *nn2w = d_in[9], *nn2b = d_in[10],
             *rootw = d_in[11], *rootb = d_in[12], *n2cw = d_in[13], *n2cb = d_in[14],
             *cnn1w = d_in[15], *cnn1b = d_in[16], *cnn2w = d_in[17], *cnn2b = d_in[18],
             *crootw = d_in[19], *crootb = d_in[20], *c2nw = d_in[21], *c2nb = d_in[22];

  char* ws = (char*)d_ws;
  size_t off = 0;
  auto alloc = [&](size_t bytes){ void* p = ws + off; off += (bytes + 255) & ~(size_t)255; return p; };

  // ---- zeroed region (single memset) ----
  size_t zstart = off;
  float* aggE0  = (float*)alloc((size_t)Nn*32*4);
  float* aggE1  = (float*)alloc((size_t)Nn*32*4);
  float* caggE0 = (float*)alloc((size_t)NCc*32*4);
  float* caggE1 = (float*)alloc((size_t)NCc*32*4);
  float* caggS0 = (float*)alloc((size_t)NCc*32*4);
  float* caggS1 = (float*)alloc((size_t)NCc*32*4);
  float* aggS0  = (float*)alloc((size_t)Nn*32*4);
  float* aggS1  = (float*)alloc((size_t)Nn*32*4);
  int* deg_nd  = (int*)alloc((size_t)Nn*4);
  int* deg_ce  = (int*)alloc((size_t)NCc*4);
  int* deg_n2c = (int*)alloc((size_t)NCc*4);
  int* deg_c2n = (int*)alloc((size_t)Nn*4);
  int* cnt_sn  = (int*)alloc((size_t)Nn*4);
  int* cnt_sc  = (int*)alloc((size_t)NCc*4);
  int* cur_n   = (int*)alloc((size_t)Nn*4);
  int* cur_c   = (int*)alloc((size_t)NCc*4);
  int* cur_an  = (int*)alloc((size_t)Nn*4);
  int* cur_ac  = (int*)alloc((size_t)NCc*4);
  u32* maxbits = (u32*)alloc(256);
  int* zcnt = (int*)((char*)maxbits + 4);
  int* flag = (int*)((char*)maxbits + 8);
  int* done = (int*)((char*)maxbits + 12);
  size_t zbytes = off - zstart;

  // ---- non-zeroed ----
  float* xB  = (float*)alloc((size_t)Nn*32*4);
  float* xC  = (float*)alloc((size_t)Nn*32*4);
  float* cC0 = (float*)alloc((size_t)NCc*32*4);
  float* cC1 = (float*)alloc((size_t)NCc*32*4);
  float* frn = (float*)alloc((size_t)Nn*32*4);
  float* frc = (float*)alloc((size_t)NCc*32*4);
  int* offs_n  = (int*)alloc((size_t)Nn*4);
  int* offs_c  = (int*)alloc((size_t)NCc*4);
  int* offs_an = (int*)alloc((size_t)Nn*4);
  int* offs_ac = (int*)alloc((size_t)NCc*4);
  int* bs0 = (int*)alloc(512); int* bs1 = (int*)alloc(512);
  int* bs2 = (int*)alloc(512); int* bs3 = (int*)alloc(512);
  int* perm_n = (int*)alloc((size_t)Ee*4);
  int* perm_c = (int*)alloc((size_t)ECc*4);
  int* an2c = (int*)alloc((size_t)Aa*4);
  int* ac2n = (int*)alloc((size_t)Aa*4);
  int2* sdp_n = (int2*)alloc((size_t)Ee*8);
  int2* sdp_c = (int2*)alloc((size_t)ECc*8);
  float* efp_n = (float*)alloc((size_t)Ee*8*4);
  float* efp_c = (float*)alloc((size_t)ECc*8*4);
  u16* Wp4 = (u16*)alloc((size_t)4*WPSZ*2);

  auto nb = [](int n){ return (n + 255)/256; };

  // 1. memset accumulators/counters
  hipMemsetAsync(ws + zstart, 0, zbytes, stream);
  // 2. dtype detect
  k_detect<<<256,256,0,stream>>>((const u16*)d_in[0], Nn*32, maxbits, zcnt, done, flag);
  // 3. histograms + 4-way scan + counting sorts + payload gather
  k_count_all<<<nb(2*Ee + 2*ECc + 2*Aa),256,0,stream>>>(ei, cei, n2c,
      deg_nd, deg_ce, deg_n2c, deg_c2n, cnt_sn, cnt_sc);
  k_scan_block<<<2*(NB_N+NB_C),256,0,stream>>>(cnt_sn, cnt_sc, deg_c2n, deg_n2c,
      offs_n, offs_c, offs_an, offs_ac, bs0, bs1, bs2, bs3);
  k_spine<<<1,512,0,stream>>>(bs0, bs1, bs2, bs3);
  k_scan_fix<<<nb(2*(Nn+NCc)),256,0,stream>>>(offs_n, offs_c, offs_an, offs_ac,
      bs0, bs1, bs2, bs3);
  k_place<<<nb(Ee+ECc+2*Aa),256,0,stream>>>(ei, cei, n2c, offs_n, offs_c, offs_an, offs_ac,
      cur_n, cur_c, cur_an, cur_ac, perm_n, perm_c, an2c, ac2n);
  k_gather<<<nb(8*(Ee+ECc)),256,0,stream>>>(ei, cei, perm_n, perm_c, efr, cefr, flag,
      sdp_n, efp_n, sdp_c, efp_c);
  // 4. pack weights
  k_wpack_all<<<nb(4*WPSZ),256,0,stream>>>(nn2w, nn2b, rootw, cnn2w, cnn2b, crootw, flag, Wp4);

  int Gn = (Nn + 15)/16, Gc = (NCc + 15)/16;

  // ---- layer 0 ----
  k_conv_fused<<<Gn,512,0,stream>>>(d_in[0], 1, nullptr, nullptr, Nn, sdp_n, efp_n, offs_n, Ee,
      nn1w, 0, nn1b, 0, Wp4 + 0*WPSZ, rootb, 0, flag, frn, aggE0);
  k_update_lin<<<(Nn+7)/8,256,0,stream>>>(aggE0, deg_nd, frn, Nn, n2cw, 0, n2cb, 0, flag,
      xB, ac2n, offs_an, deg_c2n, caggS0);
  k_conv_fused<<<Gc,512,0,stream>>>(d_in[3], 1, caggS0, deg_n2c, NCc, sdp_c, efp_c, offs_c, ECc,
      cnn1w, 0, cnn1b, 0, Wp4 + 1*WPSZ, crootb, 0, flag, frc, caggE0);
  k_update_lin<<<(NCc+7)/8,256,0,stream>>>(caggE0, deg_ce, frc, NCc, c2nw, 0, c2nb, 0, flag,
      cC0, an2c, offs_ac, deg_n2c, aggS0);
  // ---- layer 1 ----
  k_conv_fused<<<Gn,512,0,stream>>>(xB, 0, aggS0, deg_c2n, Nn, sdp_n, efp_n, offs_n, Ee,
      nn1w, 256, nn1b, 32, Wp4 + 2*WPSZ, rootb, 32, flag, frn, aggE1);
  k_update_lin<<<(Nn+7)/8,256,0,stream>>>(aggE1, deg_nd, frn, Nn, n2cw, 1024, n2cb, 32, flag,
      xC, ac2n, offs_an, deg_c2n, caggS1);
  k_conv_fused<<<Gc,512,0,stream>>>(cC0, 0, caggS1, deg_n2c, NCc, sdp_c, efp_c, offs_c, ECc,
      cnn1w, 256, cnn1b, 32, Wp4 + 3*WPSZ, crootb, 32, flag, frc, caggE1);
  k_update_lin<<<(NCc+7)/8,256,0,stream>>>(caggE1, deg_ce, frc, NCc, c2nw, 1024, c2nb, 32, flag,
      cC1, an2c, offs_ac, deg_n2c, aggS1);
  // ---- output ----
  k_store<<<nb(Nn*32 + NCc*32),256,0,stream>>>(xC, aggS1, deg_c2n, cC1, d_out, flag);
}